// Round 1
// baseline (224.264 us; speedup 1.0000x reference)
//
#include <hip/hip_runtime.h>

// MinimalSSM via MFMA, scan-free: Bu = U@B^T (bf16 MFMA), then
// H[t,s] = a_s^t * ( cumsum_{tau<=t} a_s^{-tau} Bu[tau,s] + a_s*c0_s )
// (cumsum = triangular ones-GEMM on MFMA). Y = H@C^T + U@D^T.
// R5: segment carry hierarchy: K1 -> agg + atomic segAgg (SEGL=16),
// K2 scans 128 segs, K3 parallel weighted lookback.
// R6: (a) K3 epilogue copy-out rewritten to strictly-linear mapping
//     (f = tid + 512k) so each store instruction writes 1KB of contiguous
//     full lines -- fixes remaining 2.08x WRITE_SIZE amplification.
//     (b) a_s^t factors (32 expf/thread in tri epilogue) replaced by a
//     precomputed 128x128 powA table (built in K2's idle waves, L2-hot
//     in K3); sCA removed.

#define TT   262144
#define DIN  64
#define DS   128
#define DTC  0.01f
#define L    128
#define NG   (TT / L)        // 2048 chunks
#define SEGL 16
#define NSEG (NG / SEGL)     // 128 segments

typedef short  s8v  __attribute__((ext_vector_type(8)));
typedef short  s4v  __attribute__((ext_vector_type(4)));
typedef float  f4v  __attribute__((ext_vector_type(4)));

__device__ __forceinline__ unsigned short f2bf(float f) {
    unsigned u = __float_as_uint(f);
    u += 0x7fffu + ((u >> 16) & 1u);        // round-to-nearest-even
    return (unsigned short)(u >> 16);
}

__device__ __forceinline__ s8v pack8(float4 a, float4 b) {
    union { unsigned short u[8]; s8v v; } r;
    r.u[0] = f2bf(a.x); r.u[1] = f2bf(a.y); r.u[2] = f2bf(a.z); r.u[3] = f2bf(a.w);
    r.u[4] = f2bf(b.x); r.u[5] = f2bf(b.y); r.u[6] = f2bf(b.z); r.u[7] = f2bf(b.w);
    return r.v;
}

__device__ __forceinline__ s4v pack4(float x, float y, float z, float w) {
    union { unsigned short u[4]; s4v v; } r;
    r.u[0] = f2bf(x); r.u[1] = f2bf(y); r.u[2] = f2bf(z); r.u[3] = f2bf(w);
    return r.v;
}

// Fragment-granule LDS layout for bf16 matrix X[row][col], 8-col granules:
// ushort index = ((rtile*NCO + co)*16 + (mf ^ (co&15))) * 8.
__device__ __forceinline__ int gidx(int NCO, int rtile, int co, int mf) {
    return (((rtile * NCO + co) << 4) + (mf ^ (co & 15))) << 3;
}

__device__ __forceinline__ s8v ldfrag(const unsigned short* S, int NCO,
                                      int rtile, int kt, int q, int m) {
    return *(const s8v*)&S[gidx(NCO, rtile, kt * 4 + q, m)];
}

// Stage U chunk (128 x 64 fp32) -> bf16 A-frag granules.
__device__ __forceinline__ void stage_U(const float* __restrict__ Ug,
                                        unsigned short* __restrict__ sA,
                                        int tid) {
    #pragma unroll
    for (int p = 0; p < 2; ++p) {
        int u  = tid + p * 512;
        int co = u & 7, m = (u >> 3) & 15, mt = u >> 7;
        const float4* gp = (const float4*)(Ug + (mt * 16 + m) * DIN + co * 8);
        *(s8v*)&sA[gidx(8, mt, co, m)] = pack8(gp[0], gp[1]);
    }
}

__device__ __forceinline__ s8v load_bfrag(const float* __restrict__ M,
                                          int row, int k0, int ld) {
    const float4* p = (const float4*)(M + row * ld + k0);
    return pack8(p[0], p[1]);
}

// ---------------------------------------------------------------- K1
// agg[g][s] = sum_t a_s^(L-1-t) Bu[t,s]; weighted fold into segAgg (atomic).
__global__ __launch_bounds__(512, 8) void ssm_k1(
    const float* __restrict__ U, const float* __restrict__ Alog,
    const float* __restrict__ B, float* __restrict__ agg,
    float* __restrict__ segAgg)
{
    __shared__ __align__(16) unsigned short sA[8192];   // 16 KB
    const int g    = blockIdx.x;
    const int tid  = threadIdx.x;
    const int lane = tid & 63;
    const int w    = tid >> 6;
    const int q    = lane >> 4, m = lane & 15;
    const int s    = 16 * w + m;

    stage_U(U + (size_t)g * L * DIN, sA, tid);

    s8v Bf[2];
    #pragma unroll
    for (int ks = 0; ks < 2; ++ks)
        Bf[ks] = load_bfrag(B, s, ks * 32 + q * 8, DIN);

    const float cA = Alog[s] * DTC;
    __syncthreads();

    float ainv = __expf(-cA);
    float a16i = __expf(-16.f * cA);
    float wmt  = __expf(cA * (float)(127 - 4 * q));
    float wsum = 0.f;
    #pragma unroll
    for (int mt = 0; mt < 8; ++mt) {
        f4v acc = (f4v){0.f, 0.f, 0.f, 0.f};
        #pragma unroll
        for (int ks = 0; ks < 2; ++ks)
            acc = __builtin_amdgcn_mfma_f32_16x16x32_bf16(
                ldfrag(sA, 8, mt, ks, q, m), Bf[ks], acc, 0, 0, 0);
        float wr = wmt;
        #pragma unroll
        for (int r = 0; r < 4; ++r) {
            wsum = fmaf(wr, acc[r], wsum);
            wr *= ainv;
        }
        wmt *= a16i;
    }
    wsum += __shfl_xor(wsum, 16, 64);
    wsum += __shfl_xor(wsum, 32, 64);

    if (q == 0) {
        agg[(size_t)g * DS + s] = wsum;
        float wgt = __expf(cA * (float)(L * (SEGL - 1 - (g & (SEGL - 1)))));
        atomicAdd(&segAgg[(g >> 4) * DS + s], wsum * wgt);
    }
}

// ---------------------------------------------------------------- K2
// Serial scan over 128 segment aggregates -> segment carries + h_final.
// R6: widened to 512 threads; all waves first fill powA[t][s] = a_s^t
// (128x128 fp32, 64 KB) while 2 waves then run the serial scan.
__global__ void ssm_k2(const float* __restrict__ Alog, const float* __restrict__ h0,
                       const float* __restrict__ segAgg, float* __restrict__ segCarry,
                       float* __restrict__ hfin, float* __restrict__ powA)
{
    const int tid = threadIdx.x;                             // 512 threads
    {
        const int   sc = tid & 127;
        const int   t0 = tid >> 7;                           // 0..3
        const float ca = Alog[sc] * DTC;
        #pragma unroll
        for (int k = 0; k < 32; ++k) {
            const int t = t0 + 4 * k;
            powA[t * DS + sc] = __expf(ca * (float)t);
        }
    }
    if (tid < DS) {
        const int s = tid;
        const float aSeg = __expf(Alog[s] * (DTC * L * SEGL));
        float c = h0[s];
        #pragma unroll 8
        for (int sg = 0; sg < NSEG; ++sg) {
            segCarry[sg * DS + s] = c;
            c = fmaf(aSeg, c, segAgg[sg * DS + s]);
        }
        hfin[s] = c;
    }
}

// ---------------------------------------------------------------- K3
__global__ __launch_bounds__(512, 6) void ssm_k3(
    const float* __restrict__ U, const float* __restrict__ Alog,
    const float* __restrict__ B, const float* __restrict__ C,
    const float* __restrict__ Dm, const float* __restrict__ agg,
    const float* __restrict__ segCarry, const float* __restrict__ powA,
    float* __restrict__ Y)
{
    __shared__ __align__(16) unsigned char smem[49152];      // 48 KB
    unsigned short* sA = (unsigned short*)smem;              // 16 KB U frags
    unsigned short* sT = (unsigned short*)(smem + 16384);    // 32 KB Bu'^T / H^T
    float*          sY = (float*)smem;                       // overlay, 128x68 f32
    __shared__ float sDc[DS];

    const int g    = blockIdx.x;
    const int tid  = threadIdx.x;
    const int lane = tid & 63;
    const int w    = tid >> 6;
    const int q    = lane >> 4, m = lane & 15;

    s8v Bf[2];
    #pragma unroll
    for (int ks = 0; ks < 2; ++ks)
        Bf[ks] = load_bfrag(B, 16 * w + m, ks * 32 + q * 8, DIN);
    const float cA = Alog[16 * w + m] * DTC;

    // a_s^t row for this thread's t = 16w+m (L2-hot table, hoisted so the
    // latency hides under staging + GEMM1 + tri-GEMM).
    float4 pw[8];
    #pragma unroll
    for (int ms2 = 0; ms2 < 8; ++ms2)
        pw[ms2] = *(const float4*)&powA[(16 * w + m) * DS + 16 * ms2 + 4 * q];

    stage_U(U + (size_t)g * L * DIN, sA, tid);

    // carry via parallel weighted lookback over <=15 L2-hot agg rows
    if (tid < DS) {
        const float ca  = Alog[tid] * DTC;
        const float caL = ca * (float)L;
        const float aL  = __expf(caL);
        const int   j   = g & (SEGL - 1);
        const int   gb  = g & ~(SEGL - 1);
        float c0 = segCarry[(g >> 4) * DS + tid] * __expf(caL * (float)j);
        float wt = 1.f;
        for (int c = j - 1; c >= 0; --c) {
            c0 = fmaf(wt, agg[(size_t)(gb + c) * DS + tid], c0);
            wt *= aL;
        }
        sDc[tid] = __expf(ca) * c0;             // a_s * carry_s
    }
    __syncthreads();                                     // B1

    // ---- GEMM1 + scale by a_s^-t, transpose-store Bu'^T[s][t]
    {
        float ainv = __expf(-cA);
        float a16i = __expf(-16.f * cA);
        float fmt  = __expf(-cA * (float)(4 * q));
        #pragma unroll
        for (int mt = 0; mt < 8; ++mt) {
            f4v acc = (f4v){0.f, 0.f, 0.f, 0.f};
            #pragma unroll
            for (int ks = 0; ks < 2; ++ks)
                acc = __builtin_amdgcn_mfma_f32_16x16x32_bf16(
                    ldfrag(sA, 8, mt, ks, q, m), Bf[ks], acc, 0, 0, 0);
            float f0 = fmt, f1 = f0 * ainv, f2 = f1 * ainv, f3 = f2 * ainv;
            s4v pk = pack4(acc[0] * f0, acc[1] * f1, acc[2] * f2, acc[3] * f3);
            *(s4v*)&sT[gidx(16, w, mt * 2 + (q >> 1), m) + (q & 1) * 4] = pk;
            fmt *= a16i;
        }
    }
    __syncthreads();                                     // B2

    // ---- Tri-GEMM: H'^T[s,t] = sum_{tau<=t} Bu'^T[s,tau]
    const int KBmax = w >> 1;
    const int thr   = m + 16 * (w & 1);
    s8v ones, part;
    {
        union { unsigned short u[8]; s8v v; } o, p;
        #pragma unroll
        for (int j = 0; j < 8; ++j) {
            o.u[j] = 0x3F80;
            p.u[j] = (q * 8 + j <= thr) ? 0x3F80 : 0;
        }
        ones = o.v; part = p.v;
    }
    s4v pk[8];
    #pragma unroll
    for (int grp = 0; grp < 2; ++grp) {
        f4v acc[4];
        #pragma unroll
        for (int i = 0; i < 4; ++i) acc[i] = (f4v){0.f, 0.f, 0.f, 0.f};
        for (int kb = 0; kb <= KBmax; ++kb) {
            s8v bfr = (kb < KBmax) ? ones : part;
            #pragma unroll
            for (int msl = 0; msl < 4; ++msl)
                acc[msl] = __builtin_amdgcn_mfma_f32_16x16x32_bf16(
                    ldfrag(sT, 16, grp * 4 + msl, kb, q, m), bfr, acc[msl], 0, 0, 0);
        }
        #pragma unroll
        for (int msl = 0; msl < 4; ++msl) {
            const int ms = grp * 4 + msl;
            const float4 dcv = *(const float4*)&sDc[16 * ms + 4 * q];
            const float4 pwv = pw[ms];
            pk[ms] = pack4(
                pwv.x * (acc[msl][0] + dcv.x),
                pwv.y * (acc[msl][1] + dcv.y),
                pwv.z * (acc[msl][2] + dcv.z),
                pwv.w * (acc[msl][3] + dcv.w));
        }
    }

    // C/D raw loads (latency overlapped with barriers + sT writes)
    const int mi = w & 3, th = w >> 2;
    float4 craw[4][2], draw[2][2];
    #pragma unroll
    for (int ks = 0; ks < 4; ++ks) {
        const float4* p = (const float4*)(C + (16 * mi + m) * DS + ks * 32 + q * 8);
        craw[ks][0] = p[0]; craw[ks][1] = p[1];
    }
    #pragma unroll
    for (int ks = 0; ks < 2; ++ks) {
        const float4* p = (const float4*)(Dm + (16 * mi + m) * DIN + ks * 32 + q * 8);
        draw[ks][0] = p[0]; draw[ks][1] = p[1];
    }

    __syncthreads();                                     // B3
    #pragma unroll
    for (int ms = 0; ms < 8; ++ms)
        *(s4v*)&sT[gidx(16, w, ms * 2 + (q >> 1), m) + (q & 1) * 4] = pk[ms];
    __syncthreads();                                     // B4

    // ---- GEMM2: (M=i, N=t) tiles; accs held in regs until B5
    s8v Cf[4], Df[2];
    #pragma unroll
    for (int ks = 0; ks < 4; ++ks) Cf[ks] = pack8(craw[ks][0], craw[ks][1]);
    #pragma unroll
    for (int ks = 0; ks < 2; ++ks) Df[ks] = pack8(draw[ks][0], draw[ks][1]);

    f4v acc2[4];
    #pragma unroll
    for (int nn = 0; nn < 4; ++nn) {
        const int nt2 = th * 4 + nn;
        f4v a2 = (f4v){0.f, 0.f, 0.f, 0.f};
        #pragma unroll
        for (int ks = 0; ks < 4; ++ks)
            a2 = __builtin_amdgcn_mfma_f32_16x16x32_bf16(
                Cf[ks], ldfrag(sT, 16, nt2, ks, q, m), a2, 0, 0, 0);
        #pragma unroll
        for (int ks = 0; ks < 2; ++ks)
            a2 = __builtin_amdgcn_mfma_f32_16x16x32_bf16(
                Df[ks], ldfrag(sA, 8, nt2, ks, q, m), a2, 0, 0, 0);
        acc2[nn] = a2;
    }
    __syncthreads();                                     // B5: all LDS reads done

    // stage Y in LDS (stride 68: <=2-way banks), then strictly-linear copy-out
    #pragma unroll
    for (int nn = 0; nn < 4; ++nn) {
        const int t = 16 * (th * 4 + nn) + m;
        *(f4v*)&sY[t * 68 + 16 * mi + 4 * q] = acc2[nn];
    }
    __syncthreads();                                     // B6

    // Linear mapping: float4 index f = tid + 512k. Each wave store
    // instruction covers 1 KB contiguous (16 full 64B lines) -> no
    // partial-line write amplification.
    float* Yb = Y + (size_t)g * L * DIN;
    #pragma unroll
    for (int k = 0; k < 4; ++k) {
        const int f   = tid + 512 * k;
        const int row = f >> 4;
        const int col = (f & 15) << 2;
        *(float4*)(Yb + row * 64 + col) = *(const float4*)&sY[row * 68 + col];
    }
}

// ---------------------------------------------------------------- launch
extern "C" void kernel_launch(void* const* d_in, const int* in_sizes, int n_in,
                              void* d_out, int out_size, void* d_ws, size_t ws_size,
                              hipStream_t stream)
{
    const float* U    = (const float*)d_in[0];
    const float* Alog = (const float*)d_in[1];
    const float* B    = (const float*)d_in[2];
    const float* C    = (const float*)d_in[3];
    const float* Dm   = (const float*)d_in[4];
    const float* h0   = (const float*)d_in[5];

    float* out  = (float*)d_out;
    float* Yp   = out;                        // T*DIN
    float* hfin = out + (size_t)TT * DIN;     // 128

    float* agg      = (float*)d_ws;                 // NG*DS    (1 MB)
    float* segAgg   = agg + (size_t)NG * DS;        // NSEG*DS  (64 KB)
    float* segCarry = segAgg + (size_t)NSEG * DS;   // NSEG*DS  (64 KB)
    float* powA     = segCarry + (size_t)NSEG * DS; // DS*DS    (64 KB)

    hipMemsetAsync(segAgg, 0, (size_t)NSEG * DS * sizeof(float), stream);
    ssm_k1<<<NG, 512, 0, stream>>>(U, Alog, B, agg, segAgg);
    ssm_k2<<<1, 512, 0, stream>>>(Alog, h0, segAgg, segCarry, hfin, powA);
    ssm_k3<<<NG, 512, 0, stream>>>(U, Alog, B, C, Dm, agg, segCarry, powA, Yp);
}

// Round 2
// 199.378 us; speedup vs baseline: 1.1248x; 1.1248x over previous
//
#include <hip/hip_runtime.h>

// MinimalSSM via MFMA, scan-free: Bu = U@B^T (bf16 MFMA), then
// H[t,s] = a_s^t * ( cumsum_{tau<=t} a_s^{-tau} Bu[tau,s] + a_s*c0_s )
// (cumsum = triangular ones-GEMM on MFMA). Y = H@C^T + U@D^T.
// R5: segment carry hierarchy: K1 -> agg + atomic segAgg (SEGL=16),
// K2 scans 128 segs, K3 parallel weighted lookback.
// R7: R6's powA table REVERTED (it spilled pw[8] to scratch: +78MB write
// +43MB fetch of deterministic per-thread spill traffic, K3 87->116us).
// Kept ONLY the linear copy-out: f = tid + 512k -> addr = Yb + 16f bytes,
// each wave store instruction covers 1KB of full contiguous lines.

#define TT   262144
#define DIN  64
#define DS   128
#define DTC  0.01f
#define L    128
#define NG   (TT / L)        // 2048 chunks
#define SEGL 16
#define NSEG (NG / SEGL)     // 128 segments

typedef short  s8v  __attribute__((ext_vector_type(8)));
typedef short  s4v  __attribute__((ext_vector_type(4)));
typedef float  f4v  __attribute__((ext_vector_type(4)));

__device__ __forceinline__ unsigned short f2bf(float f) {
    unsigned u = __float_as_uint(f);
    u += 0x7fffu + ((u >> 16) & 1u);        // round-to-nearest-even
    return (unsigned short)(u >> 16);
}

__device__ __forceinline__ s8v pack8(float4 a, float4 b) {
    union { unsigned short u[8]; s8v v; } r;
    r.u[0] = f2bf(a.x); r.u[1] = f2bf(a.y); r.u[2] = f2bf(a.z); r.u[3] = f2bf(a.w);
    r.u[4] = f2bf(b.x); r.u[5] = f2bf(b.y); r.u[6] = f2bf(b.z); r.u[7] = f2bf(b.w);
    return r.v;
}

__device__ __forceinline__ s4v pack4(float x, float y, float z, float w) {
    union { unsigned short u[4]; s4v v; } r;
    r.u[0] = f2bf(x); r.u[1] = f2bf(y); r.u[2] = f2bf(z); r.u[3] = f2bf(w);
    return r.v;
}

// Fragment-granule LDS layout for bf16 matrix X[row][col], 8-col granules:
// ushort index = ((rtile*NCO + co)*16 + (mf ^ (co&15))) * 8.
__device__ __forceinline__ int gidx(int NCO, int rtile, int co, int mf) {
    return (((rtile * NCO + co) << 4) + (mf ^ (co & 15))) << 3;
}

__device__ __forceinline__ s8v ldfrag(const unsigned short* S, int NCO,
                                      int rtile, int kt, int q, int m) {
    return *(const s8v*)&S[gidx(NCO, rtile, kt * 4 + q, m)];
}

// Stage U chunk (128 x 64 fp32) -> bf16 A-frag granules.
__device__ __forceinline__ void stage_U(const float* __restrict__ Ug,
                                        unsigned short* __restrict__ sA,
                                        int tid) {
    #pragma unroll
    for (int p = 0; p < 2; ++p) {
        int u  = tid + p * 512;
        int co = u & 7, m = (u >> 3) & 15, mt = u >> 7;
        const float4* gp = (const float4*)(Ug + (mt * 16 + m) * DIN + co * 8);
        *(s8v*)&sA[gidx(8, mt, co, m)] = pack8(gp[0], gp[1]);
    }
}

__device__ __forceinline__ s8v load_bfrag(const float* __restrict__ M,
                                          int row, int k0, int ld) {
    const float4* p = (const float4*)(M + row * ld + k0);
    return pack8(p[0], p[1]);
}

// ---------------------------------------------------------------- K1
// agg[g][s] = sum_t a_s^(L-1-t) Bu[t,s]; weighted fold into segAgg (atomic).
__global__ __launch_bounds__(512, 8) void ssm_k1(
    const float* __restrict__ U, const float* __restrict__ Alog,
    const float* __restrict__ B, float* __restrict__ agg,
    float* __restrict__ segAgg)
{
    __shared__ __align__(16) unsigned short sA[8192];   // 16 KB
    const int g    = blockIdx.x;
    const int tid  = threadIdx.x;
    const int lane = tid & 63;
    const int w    = tid >> 6;
    const int q    = lane >> 4, m = lane & 15;
    const int s    = 16 * w + m;

    stage_U(U + (size_t)g * L * DIN, sA, tid);

    s8v Bf[2];
    #pragma unroll
    for (int ks = 0; ks < 2; ++ks)
        Bf[ks] = load_bfrag(B, s, ks * 32 + q * 8, DIN);

    const float cA = Alog[s] * DTC;
    __syncthreads();

    float ainv = __expf(-cA);
    float a16i = __expf(-16.f * cA);
    float wmt  = __expf(cA * (float)(127 - 4 * q));
    float wsum = 0.f;
    #pragma unroll
    for (int mt = 0; mt < 8; ++mt) {
        f4v acc = (f4v){0.f, 0.f, 0.f, 0.f};
        #pragma unroll
        for (int ks = 0; ks < 2; ++ks)
            acc = __builtin_amdgcn_mfma_f32_16x16x32_bf16(
                ldfrag(sA, 8, mt, ks, q, m), Bf[ks], acc, 0, 0, 0);
        float wr = wmt;
        #pragma unroll
        for (int r = 0; r < 4; ++r) {
            wsum = fmaf(wr, acc[r], wsum);
            wr *= ainv;
        }
        wmt *= a16i;
    }
    wsum += __shfl_xor(wsum, 16, 64);
    wsum += __shfl_xor(wsum, 32, 64);

    if (q == 0) {
        agg[(size_t)g * DS + s] = wsum;
        float wgt = __expf(cA * (float)(L * (SEGL - 1 - (g & (SEGL - 1)))));
        atomicAdd(&segAgg[(g >> 4) * DS + s], wsum * wgt);
    }
}

// ---------------------------------------------------------------- K2
// Serial scan over 128 segment aggregates -> segment carries + h_final.
__global__ void ssm_k2(const float* __restrict__ Alog, const float* __restrict__ h0,
                       const float* __restrict__ segAgg, float* __restrict__ segCarry,
                       float* __restrict__ hfin)
{
    const int s = threadIdx.x;                               // 128 threads
    const float aSeg = __expf(Alog[s] * (DTC * L * SEGL));
    float c = h0[s];
    #pragma unroll 8
    for (int sg = 0; sg < NSEG; ++sg) {
        segCarry[sg * DS + s] = c;
        c = fmaf(aSeg, c, segAgg[sg * DS + s]);
    }
    hfin[s] = c;
}

// ---------------------------------------------------------------- K3
__global__ __launch_bounds__(512, 6) void ssm_k3(
    const float* __restrict__ U, const float* __restrict__ Alog,
    const float* __restrict__ B, const float* __restrict__ C,
    const float* __restrict__ Dm, const float* __restrict__ agg,
    const float* __restrict__ segCarry, float* __restrict__ Y)
{
    __shared__ __align__(16) unsigned char smem[49152];      // 48 KB
    unsigned short* sA = (unsigned short*)smem;              // 16 KB U frags
    unsigned short* sT = (unsigned short*)(smem + 16384);    // 32 KB Bu'^T / H^T
    float*          sY = (float*)smem;                       // overlay, 128x68 f32
    __shared__ float sCA[DS];
    __shared__ float sDc[DS];

    const int g    = blockIdx.x;
    const int tid  = threadIdx.x;
    const int lane = tid & 63;
    const int w    = tid >> 6;
    const int q    = lane >> 4, m = lane & 15;

    s8v Bf[2];
    #pragma unroll
    for (int ks = 0; ks < 2; ++ks)
        Bf[ks] = load_bfrag(B, 16 * w + m, ks * 32 + q * 8, DIN);
    const float cA = Alog[16 * w + m] * DTC;

    stage_U(U + (size_t)g * L * DIN, sA, tid);

    // carry via parallel weighted lookback over <=15 L2-hot agg rows
    if (tid < DS) {
        const float ca  = Alog[tid] * DTC;
        sCA[tid] = ca;
        const float caL = ca * (float)L;
        const float aL  = __expf(caL);
        const int   j   = g & (SEGL - 1);
        const int   gb  = g & ~(SEGL - 1);
        float c0 = segCarry[(g >> 4) * DS + tid] * __expf(caL * (float)j);
        float wt = 1.f;
        for (int c = j - 1; c >= 0; --c) {
            c0 = fmaf(wt, agg[(size_t)(gb + c) * DS + tid], c0);
            wt *= aL;
        }
        sDc[tid] = __expf(ca) * c0;             // a_s * carry_s
    }
    __syncthreads();                                     // B1

    // ---- GEMM1 + scale by a_s^-t, transpose-store Bu'^T[s][t]
    {
        float ainv = __expf(-cA);
        float a16i = __expf(-16.f * cA);
        float fmt  = __expf(-cA * (float)(4 * q));
        #pragma unroll
        for (int mt = 0; mt < 8; ++mt) {
            f4v acc = (f4v){0.f, 0.f, 0.f, 0.f};
            #pragma unroll
            for (int ks = 0; ks < 2; ++ks)
                acc = __builtin_amdgcn_mfma_f32_16x16x32_bf16(
                    ldfrag(sA, 8, mt, ks, q, m), Bf[ks], acc, 0, 0, 0);
            float f0 = fmt, f1 = f0 * ainv, f2 = f1 * ainv, f3 = f2 * ainv;
            s4v pk = pack4(acc[0] * f0, acc[1] * f1, acc[2] * f2, acc[3] * f3);
            *(s4v*)&sT[gidx(16, w, mt * 2 + (q >> 1), m) + (q & 1) * 4] = pk;
            fmt *= a16i;
        }
    }
    __syncthreads();                                     // B2

    // ---- Tri-GEMM: H'^T[s,t] = sum_{tau<=t} Bu'^T[s,tau]
    const int KBmax = w >> 1;
    const int thr   = m + 16 * (w & 1);
    s8v ones, part;
    {
        union { unsigned short u[8]; s8v v; } o, p;
        #pragma unroll
        for (int j = 0; j < 8; ++j) {
            o.u[j] = 0x3F80;
            p.u[j] = (q * 8 + j <= thr) ? 0x3F80 : 0;
        }
        ones = o.v; part = p.v;
    }
    const float tf = (float)(16 * w + m);
    s4v pk[8];
    #pragma unroll
    for (int grp = 0; grp < 2; ++grp) {
        f4v acc[4];
        #pragma unroll
        for (int i = 0; i < 4; ++i) acc[i] = (f4v){0.f, 0.f, 0.f, 0.f};
        for (int kb = 0; kb <= KBmax; ++kb) {
            s8v bfr = (kb < KBmax) ? ones : part;
            #pragma unroll
            for (int msl = 0; msl < 4; ++msl)
                acc[msl] = __builtin_amdgcn_mfma_f32_16x16x32_bf16(
                    ldfrag(sT, 16, grp * 4 + msl, kb, q, m), bfr, acc[msl], 0, 0, 0);
        }
        #pragma unroll
        for (int msl = 0; msl < 4; ++msl) {
            const int ms = grp * 4 + msl;
            const float4 cav = *(const float4*)&sCA[16 * ms + 4 * q];
            const float4 dcv = *(const float4*)&sDc[16 * ms + 4 * q];
            pk[grp * 4 + msl] = pack4(
                __expf(cav.x * tf) * (acc[msl][0] + dcv.x),
                __expf(cav.y * tf) * (acc[msl][1] + dcv.y),
                __expf(cav.z * tf) * (acc[msl][2] + dcv.z),
                __expf(cav.w * tf) * (acc[msl][3] + dcv.w));
        }
    }

    // C/D raw loads (latency overlapped with barriers + sT writes)
    const int mi = w & 3, th = w >> 2;
    float4 craw[4][2], draw[2][2];
    #pragma unroll
    for (int ks = 0; ks < 4; ++ks) {
        const float4* p = (const float4*)(C + (16 * mi + m) * DS + ks * 32 + q * 8);
        craw[ks][0] = p[0]; craw[ks][1] = p[1];
    }
    #pragma unroll
    for (int ks = 0; ks < 2; ++ks) {
        const float4* p = (const float4*)(Dm + (16 * mi + m) * DIN + ks * 32 + q * 8);
        draw[ks][0] = p[0]; draw[ks][1] = p[1];
    }

    __syncthreads();                                     // B3
    #pragma unroll
    for (int ms = 0; ms < 8; ++ms)
        *(s4v*)&sT[gidx(16, w, ms * 2 + (q >> 1), m) + (q & 1) * 4] = pk[ms];
    __syncthreads();                                     // B4

    // ---- GEMM2: (M=i, N=t) tiles; accs held in regs until B5
    s8v Cf[4], Df[2];
    #pragma unroll
    for (int ks = 0; ks < 4; ++ks) Cf[ks] = pack8(craw[ks][0], craw[ks][1]);
    #pragma unroll
    for (int ks = 0; ks < 2; ++ks) Df[ks] = pack8(draw[ks][0], draw[ks][1]);

    f4v acc2[4];
    #pragma unroll
    for (int nn = 0; nn < 4; ++nn) {
        const int nt2 = th * 4 + nn;
        f4v a2 = (f4v){0.f, 0.f, 0.f, 0.f};
        #pragma unroll
        for (int ks = 0; ks < 4; ++ks)
            a2 = __builtin_amdgcn_mfma_f32_16x16x32_bf16(
                Cf[ks], ldfrag(sT, 16, nt2, ks, q, m), a2, 0, 0, 0);
        #pragma unroll
        for (int ks = 0; ks < 2; ++ks)
            a2 = __builtin_amdgcn_mfma_f32_16x16x32_bf16(
                Df[ks], ldfrag(sA, 8, nt2, ks, q, m), a2, 0, 0, 0);
        acc2[nn] = a2;
    }
    __syncthreads();                                     // B5: all LDS reads done

    // stage Y in LDS (stride 68: <=2-way banks), then strictly-linear copy-out
    #pragma unroll
    for (int nn = 0; nn < 4; ++nn) {
        const int t = 16 * (th * 4 + nn) + m;
        *(f4v*)&sY[t * 68 + 16 * mi + 4 * q] = acc2[nn];
    }
    __syncthreads();                                     // B6

    // Linear mapping: float4 index f = tid + 512k -> byte addr = Yb*4 + 16f.
    // Each wave store instruction covers 1 KB contiguous (16 full 64B lines).
    float* Yb = Y + (size_t)g * L * DIN;
    #pragma unroll
    for (int k = 0; k < 4; ++k) {
        const int f   = tid + 512 * k;
        const int row = f >> 4;
        const int col = (f & 15) << 2;
        *(float4*)(Yb + row * 64 + col) = *(const float4*)&sY[row * 68 + col];
    }
}

// ---------------------------------------------------------------- launch
extern "C" void kernel_launch(void* const* d_in, const int* in_sizes, int n_in,
                              void* d_out, int out_size, void* d_ws, size_t ws_size,
                              hipStream_t stream)
{
    const float* U    = (const float*)d_in[0];
    const float* Alog = (const float*)d_in[1];
    const float* B    = (const float*)d_in[2];
    const float* C    = (const float*)d_in[3];
    const float* Dm   = (const float*)d_in[4];
    const float* h0   = (const float*)d_in[5];

    float* out  = (float*)d_out;
    float* Yp   = out;                        // T*DIN
    float* hfin = out + (size_t)TT * DIN;     // 128

    float* agg      = (float*)d_ws;                 // NG*DS    (1 MB)
    float* segAgg   = agg + (size_t)NG * DS;        // NSEG*DS  (64 KB)
    float* segCarry = segAgg + (size_t)NSEG * DS;   // NSEG*DS  (64 KB)

    hipMemsetAsync(segAgg, 0, (size_t)NSEG * DS * sizeof(float), stream);
    ssm_k1<<<NG, 512, 0, stream>>>(U, Alog, B, agg, segAgg);
    ssm_k2<<<1, DS, 0, stream>>>(Alog, h0, segAgg, segCarry, hfin);
    ssm_k3<<<NG, 512, 0, stream>>>(U, Alog, B, C, Dm, agg, segCarry, Yp);
}